// Round 15
// baseline (180.429 us; speedup 1.0000x reference)
//
#include <hip/hip_runtime.h>
#include <hip/hip_bf16.h>

#define LL 16
#define TT 32768
#define BB 8
#define TILE 1024                 // output t per block
#define BASEI 1152                // LDS row u = tau + BASEI (512-rounded halo)
#define NSLOT 2176                // rows per buffer
#define BUFB (NSLOT * 32)         // bytes per buffer (69632)

typedef unsigned int uint;
typedef unsigned short ushort;
typedef uint  u32x4 __attribute__((ext_vector_type(4)));
typedef float f32x4 __attribute__((ext_vector_type(4)));
typedef float f32p2 __attribute__((ext_vector_type(2)));   // packed f32 pair
typedef float f32x16 __attribute__((ext_vector_type(16)));
typedef short s16x8 __attribute__((ext_vector_type(8)));   // 8 bf16

#define S_T 2.885390081777927f     // 2*log2(e)  (tanh rows prescale)
#define S_S -1.4426950408889634f   // -log2(e)   (sigmoid rows prescale)

template <int N> struct IC { static constexpr int value = N; };

__device__ __forceinline__ ushort f2bf(float f) {
  uint u = __float_as_uint(f);
  return (ushort)((u + 0x7FFFu + ((u >> 16) & 1u)) >> 16);   // RNE
}
__device__ __forceinline__ uint cvtpk(float lo, float hi) {
  __hip_bfloat162 h = __float22bfloat162_rn(float2{lo, hi});
  uint r;
  __builtin_memcpy(&r, &h, 4);
  return r;
}
__device__ __forceinline__ float fexp2(float x) {
#if __has_builtin(__builtin_amdgcn_exp2f)
  return __builtin_amdgcn_exp2f(x);
#else
  return exp2f(x);
#endif
}
__device__ __forceinline__ f32x16 mfma32(s16x8 a, s16x8 b, f32x16 c) {
  return __builtin_amdgcn_mfma_f32_32x32x16_bf16(a, b, c, 0, 0, 0);
}
// swizzle: addr = swzb(u) ^ o (o < 32); swzb(u+512) = swzb(u)+16384.
// oG (bit 4 only) XOR-commutes with all +k used here (k multiples of 2^12),
// so it is folded into the per-layer bases once.
__device__ __forceinline__ int swzb(int u) {
  return (u << 5) ^ ((u & 28) << 2);
}
__device__ __forceinline__ int swz(int u, int o) { return swzb(u) ^ o; }

// ---------------- prep: pack weights into 32x32x16 fragment order -----------
// stored-position p holds real channel perm[p] = (p&3)+8*((p>>2)&1)+4*(p>>3)
// WA[l][kt][lane][j]: A row co=lane&31, K-slot -> perm'd channel; rows<16
//   prescaled S_T (tanh), rows>=16 S_S (sigmoid).
// RA[l][0]: rows 0-15 res weight; row 16 = mix_w (skip dot rides the MFMA).
// RA[l][1]: rows 0-15 identity (residual add); rest 0.
__global__ __launch_bounds__(256) void wn_prep(
    const float* __restrict__ hw, const float* __restrict__ rw,
    const float* __restrict__ mixw,
    ushort* __restrict__ WA, ushort* __restrict__ RA) {
  int tid = blockIdx.x * 256 + threadIdx.x;      // 40960 total
  if (tid < 24576) {
    int j = tid & 7, lane = (tid >> 3) & 63;
    int rem = tid >> 9;                          // l*3 + kt
    int kt = rem % 3, l = rem / 3;
    int row = lane & 31;
    int pci = (j & 3) + ((j & 4) << 1) + ((lane >> 5) << 2);   // perm[s]
    float scale = (row < 16) ? S_T : S_S;
    WA[tid] = f2bf(hw[((l * 32 + row) * 16 + pci) * 3 + kt] * scale);
  } else if (tid < 40960) {
    int r = tid - 24576;
    int j = r & 7, lane = (r >> 3) & 63;
    int rem = r >> 9;                            // l*2 + which
    int which = rem & 1, l = rem >> 1;
    int row = lane & 31;
    int pci = (j & 3) + ((j & 4) << 1) + ((lane >> 5) << 2);   // perm[s]
    float v = 0.f;
    if (which == 0) {
      if (row < 16)       v = rw[(l * 16 + row) * 16 + pci];
      else if (row == 16) v = mixw[l * 16 + pci];              // skip row
    } else {
      if (row < 16) v = (row == pci) ? 1.f : 0.f;              // identity
    }
    RA[r] = f2bf(v);
  }
}

// ---------------- fully fused WaveNet, 32x32 MFMA bodies ---------------------
__global__ __launch_bounds__(1024, 4) void wn_fused(
    const float* __restrict__ x, const float* __restrict__ in_w,
    const float* __restrict__ in_b,
    const ushort* __restrict__ WA, const ushort* __restrict__ RA,
    const float* __restrict__ hid_b, const float* __restrict__ res_b,
    const float* __restrict__ mix_w, const float* __restrict__ mix_b,
    float* __restrict__ outp) {
  __shared__ ushort sbuf[2][NSLOT * 16];   // 2 x 69632 B, swizzled [t][16ch] bf16

  int tid = threadIdx.x;
  int b = blockIdx.x & 7, tile = blockIdx.x >> 3;   // XCD<->batch affinity
  int t0 = tile * TILE;
  char* lds = (char*)sbuf;

  // ---- stage: input 1x1 conv into buf0 over tau in [-1152, 1024) ----
  for (int r = tid; r < NSLOT; r += 1024) {
    int t = t0 + r - BASEI;
    uint pk[8];
    if (t >= 0) {
      float xv = x[b * TT + t];
#pragma unroll
      for (int c = 0; c < 8; ++c) {
        float lo = fmaf(in_w[2 * c], xv, in_b[2 * c]);
        float hi = fmaf(in_w[2 * c + 1], xv, in_b[2 * c + 1]);
        pk[c] = cvtpk(lo, hi);
      }
    } else {
#pragma unroll
      for (int c = 0; c < 8; ++c) pk[c] = 0u;     // causal zero pad
    }
    // channel-permuted word order
    *(u32x4*)(lds + swz(r, 0))  = (u32x4){pk[0], pk[1], pk[4], pk[5]};
    *(u32x4*)(lds + swz(r, 16)) = (u32x4){pk[2], pk[3], pk[6], pk[7]};
  }
  __syncthreads();

  int lane = tid & 63, w = tid >> 6;
  int col32 = lane & 31, hi = lane >> 5;
  int oG  = hi << 4;          // B-frag load AND res-write byte offset (folded)
  int X = w * 32 + col32;     // this lane's output t (chunk A); B = X+512
  float skipA = 0.f, skipB = 0.f;
  int cur = 0;

  // ---- layer-0 weight/bias preload (register software pipeline) ----
  const s16x8* wap = (const s16x8*)WA;
  s16x8 wa0 = wap[lane], wa1 = wap[64 + lane], wa2 = wap[128 + lane];
  const s16x8* rpp = (const s16x8*)RA;
  s16x8 ra1 = rpp[lane], ra2 = rpp[64 + lane];
  f32x4 hb0 = *(const f32x4*)(hid_b + 4 * hi);
  f32x4 hb1 = *(const f32x4*)(hid_b + 8 + 4 * hi);
  f32x4 hb2 = *(const f32x4*)(hid_b + 16 + 4 * hi);
  f32x4 hb3 = *(const f32x4*)(hid_b + 24 + 4 * hi);
  f32x4 rb0 = *(const f32x4*)(res_b + 4 * hi);
  f32x4 rb1 = *(const f32x4*)(res_b + 8 + 4 * hi);

  for (int i = 0; i < LL; ++i) {
    int D = 1 << (i & 7);
    int ost = (i < 7) ? -1024 : ((i < 15) ? -512 : 0);   // 512-rounded spans
    bool last = (i == LL - 1);

    // bias fragments, prescaled to exp2 domain (from prefetched regs)
    f32x16 bini;
#pragma unroll
    for (int q = 0; q < 4; ++q) {
      bini[q] = hb0[q] * S_T; bini[4 + q] = hb1[q] * S_T;
      bini[8 + q] = hb2[q] * S_S; bini[12 + q] = hb3[q] * S_S;
    }
    f32x16 rini;
#pragma unroll
    for (int q = 0; q < 4; ++q) {
      rini[q] = rb0[q]; rini[4 + q] = rb1[q];
      rini[8 + q] = 0.f; rini[12 + q] = 0.f;
    }
    f32x4 mwA, mwB;
    if (last) {
      mwA = *(const f32x4*)(mix_w + i * 16 + 4 * hi);
      mwB = *(const f32x4*)(mix_w + i * 16 + 8 + 4 * hi);
    }

    // ---- issue next layer's weight/bias loads now; consumed after barrier ----
    s16x8 nwa0, nwa1, nwa2, nra1, nra2;
    f32x4 nhb0, nhb1, nhb2, nhb3, nrb0, nrb1;
    if (i + 1 < LL) {
      const s16x8* wan = (const s16x8*)(WA + (size_t)(i + 1) * 1536);
      nwa0 = wan[lane]; nwa1 = wan[64 + lane]; nwa2 = wan[128 + lane];
      const s16x8* ran = (const s16x8*)(RA + (size_t)(i + 1) * 1024);
      nra1 = ran[lane]; nra2 = ran[64 + lane];
      nhb0 = *(const f32x4*)(hid_b + (i + 1) * 32 + 4 * hi);
      nhb1 = *(const f32x4*)(hid_b + (i + 1) * 32 + 8 + 4 * hi);
      nhb2 = *(const f32x4*)(hid_b + (i + 1) * 32 + 16 + 4 * hi);
      nhb3 = *(const f32x4*)(hid_b + (i + 1) * 32 + 24 + 4 * hi);
      nrb0 = *(const f32x4*)(res_b + (i + 1) * 16 + 4 * hi);
      nrb1 = *(const f32x4*)(res_b + (i + 1) * 16 + 8 + 4 * hi);
    }

    int rb = cur * BUFB;
    int wdelta = cur ? -BUFB : BUFB;
    int u0 = ost + X + BASEI;
    // oG folded into bases (bit-4 XOR commutes with all later adds)
    int A2 = (rb + swzb(u0)) ^ oG;
    int A1 = (rb + swzb(u0 - D)) ^ oG;
    int A0 = (rb + swzb(u0 - 2 * D)) ^ oG;
    int AW = A2 + wdelta;
    int tb0 = t0 + ost + X;

    // NB bodies: NB-2 halo, then output A, output B. Depth-1 tap pipeline.
    auto run = [&](auto nbc) {
      constexpr int NB = decltype(nbc)::value;
      s16x8 c0 = *(const s16x8*)(lds + A0);
      s16x8 c1 = *(const s16x8*)(lds + A1);
      s16x8 c2 = *(const s16x8*)(lds + A2);
#pragma unroll
      for (int bb = 0; bb < NB; ++bb) {
        const int mode = (bb < NB - 2) ? 0 : ((bb == NB - 2) ? 1 : 2);
        s16x8 n0, n1, n2;
        if (bb + 1 < NB) {        // prefetch next body's taps
          n0 = *(const s16x8*)(lds + A0 + (bb + 1) * 16384);
          n1 = *(const s16x8*)(lds + A1 + (bb + 1) * 16384);
          n2 = *(const s16x8*)(lds + A2 + (bb + 1) * 16384);
        }

        f32x16 acc = mfma32(wa0, c0, bini);
        acc = mfma32(wa1, c1, acc);
        acc = mfma32(wa2, c2, acc);

        // gated = (E-1)/((E+1)(F+1)); packed-f32 arithmetic, exp2 domain
        f32p2 G[4];
#pragma unroll
        for (int p = 0; p < 4; ++p) {
          f32p2 E = {fexp2(acc[2 * p]), fexp2(acc[2 * p + 1])};
          f32p2 F = {fexp2(acc[2 * p + 8]), fexp2(acc[2 * p + 9])};
          f32p2 num = E - 1.f;
          f32p2 den = (E + 1.f) * (F + 1.f);
          f32p2 R = {__builtin_amdgcn_rcpf(den.x), __builtin_amdgcn_rcpf(den.y)};
          G[p] = num * R;
        }

        if (!last) {
          uint O0 = cvtpk(G[0].x, G[0].y);
          uint O1 = cvtpk(G[1].x, G[1].y);
          uint O2 = cvtpk(G[2].x, G[2].y);
          uint O3 = cvtpk(G[3].x, G[3].y);
          u32x4 gw = {O0, O1, O2, O3};
          s16x8 gb = __builtin_bit_cast(s16x8, gw);

          f32x16 accr = mfma32(ra1, gb, rini);   // R@gates + res_b; row16=mix
          accr = mfma32(ra2, c2, accr);          // + identity @ center taps

          if (mode == 1) skipA += accr[8];       // row16 (hi=1 adds 0)
          else if (mode == 2) skipB += accr[8];

          uint o0 = cvtpk(accr[0], accr[1]);
          uint o1 = cvtpk(accr[2], accr[3]);
          uint o2 = cvtpk(accr[4], accr[5]);
          uint o3 = cvtpk(accr[6], accr[7]);
          if (mode == 0 && (tb0 + 512 * bb) < 0) { o0 = o1 = o2 = o3 = 0u; }
          *(u32x4*)(lds + AW + bb * 16384) = (u32x4){o0, o1, o2, o3};
        } else {
          float s = G[0].x * mwA[0];
          s = fmaf(G[0].y, mwA[1], s);
          s = fmaf(G[1].x, mwA[2], s);
          s = fmaf(G[1].y, mwA[3], s);
          s = fmaf(G[2].x, mwB[0], s);
          s = fmaf(G[2].y, mwB[1], s);
          s = fmaf(G[3].x, mwB[2], s);
          s = fmaf(G[3].y, mwB[3], s);
          if (mode == 1) skipA += s; else skipB += s;
        }

        c0 = n0; c1 = n1; c2 = n2;   // renamed away by full unroll
      }
    };

    if (i < 7)       run(IC<4>{});
    else if (i < 15) run(IC<3>{});
    else             run(IC<2>{});

    __syncthreads();
    cur ^= 1;
    if (i + 1 < LL) {   // rotate prefetched weights in
      wa0 = nwa0; wa1 = nwa1; wa2 = nwa2; ra1 = nra1; ra2 = nra2;
      hb0 = nhb0; hb1 = nhb1; hb2 = nhb2; hb3 = nhb3;
      rb0 = nrb0; rb1 = nrb1;
    }
  }

  // epilogue: sum hi halves, write output directly
  float totA = skipA + __shfl_xor(skipA, 32);
  float totB = skipB + __shfl_xor(skipB, 32);
  if (hi == 0) {
    float mb = mix_b[0];
    int base = b * TT + t0 + X;
    outp[base] = totA + mb;
    outp[base + 512] = totB + mb;
  }
}

extern "C" void kernel_launch(void* const* d_in, const int* in_sizes, int n_in,
                              void* d_out, int out_size, void* d_ws, size_t ws_size,
                              hipStream_t stream) {
  const float* x     = (const float*)d_in[0];
  const float* in_w  = (const float*)d_in[1];
  const float* in_b  = (const float*)d_in[2];
  const float* hid_w = (const float*)d_in[3];
  const float* hid_b = (const float*)d_in[4];
  const float* res_w = (const float*)d_in[5];
  const float* res_b = (const float*)d_in[6];
  const float* mix_w = (const float*)d_in[7];
  const float* mix_b = (const float*)d_in[8];
  float* outp = (float*)d_out;

  ushort* WA = (ushort*)d_ws;          // 24576 ushorts
  ushort* RA = WA + 24576;             // 16384 ushorts

  wn_prep<<<160, 256, 0, stream>>>(hid_w, res_w, mix_w, WA, RA);
  wn_fused<<<BB * (TT / TILE), 1024, 0, stream>>>(
      x, in_w, in_b, WA, RA, hid_b, res_b, mix_w, mix_b, outp);
}

// Round 16
// 74.593 us; speedup vs baseline: 2.4188x; 2.4188x over previous
//
#include <hip/hip_runtime.h>
#include <hip/hip_bf16.h>

#define LL 16
#define TT 32768
#define BB 8
#define TILE 1024                 // output t per block
#define BASEI 1152                // LDS row u = tau + BASEI (512-rounded halo)
#define NSLOT 2176                // rows per buffer
#define BUFB (NSLOT * 32)         // bytes per buffer (69632)

typedef unsigned int uint;
typedef unsigned short ushort;
typedef uint  u32x4 __attribute__((ext_vector_type(4)));
typedef float f32x4 __attribute__((ext_vector_type(4)));
typedef float f32p2 __attribute__((ext_vector_type(2)));   // packed f32 pair
typedef float f32x16 __attribute__((ext_vector_type(16)));
typedef short s16x8 __attribute__((ext_vector_type(8)));   // 8 bf16

#define S_T 2.885390081777927f     // 2*log2(e)  (tanh rows prescale)
#define S_S -1.4426950408889634f   // -log2(e)   (sigmoid rows prescale)

template <int N> struct IC { static constexpr int value = N; };

__device__ __forceinline__ ushort f2bf(float f) {
  uint u = __float_as_uint(f);
  return (ushort)((u + 0x7FFFu + ((u >> 16) & 1u)) >> 16);   // RNE
}
__device__ __forceinline__ uint cvtpk(float lo, float hi) {
  __hip_bfloat162 h = __float22bfloat162_rn(float2{lo, hi});
  uint r;
  __builtin_memcpy(&r, &h, 4);
  return r;
}
__device__ __forceinline__ float fexp2(float x) {
#if __has_builtin(__builtin_amdgcn_exp2f)
  return __builtin_amdgcn_exp2f(x);
#else
  return exp2f(x);
#endif
}
__device__ __forceinline__ f32x16 mfma32(s16x8 a, s16x8 b, f32x16 c) {
  return __builtin_amdgcn_mfma_f32_32x32x16_bf16(a, b, c, 0, 0, 0);
}
// swizzle: addr = swzb(u) ^ o (o < 32); swzb(u+512) = swzb(u)+16384.
// oG (bit 4 only) XOR-commutes with all later adds (multiples of 2^12),
// so it is folded into the per-layer bases once.
__device__ __forceinline__ int swzb(int u) {
  return (u << 5) ^ ((u & 28) << 2);
}
__device__ __forceinline__ int swz(int u, int o) { return swzb(u) ^ o; }

// ---------------- prep: pack weights into 32x32x16 fragment order -----------
// stored-position p holds real channel perm[p] = (p&3)+8*((p>>2)&1)+4*(p>>3)
// WA[l][kt][lane][j]: A row co=lane&31, K-slot -> perm'd channel; rows<16
//   prescaled S_T (tanh), rows>=16 S_S (sigmoid).
// RA[l][0]: rows 0-15 res weight; row 16 = mix_w (skip dot rides the MFMA).
// RA[l][1]: rows 0-15 identity (residual add); rest 0.
__global__ __launch_bounds__(256) void wn_prep(
    const float* __restrict__ hw, const float* __restrict__ rw,
    const float* __restrict__ mixw,
    ushort* __restrict__ WA, ushort* __restrict__ RA) {
  int tid = blockIdx.x * 256 + threadIdx.x;      // 40960 total
  if (tid < 24576) {
    int j = tid & 7, lane = (tid >> 3) & 63;
    int rem = tid >> 9;                          // l*3 + kt
    int kt = rem % 3, l = rem / 3;
    int row = lane & 31;
    int pci = (j & 3) + ((j & 4) << 1) + ((lane >> 5) << 2);   // perm[s]
    float scale = (row < 16) ? S_T : S_S;
    WA[tid] = f2bf(hw[((l * 32 + row) * 16 + pci) * 3 + kt] * scale);
  } else if (tid < 40960) {
    int r = tid - 24576;
    int j = r & 7, lane = (r >> 3) & 63;
    int rem = r >> 9;                            // l*2 + which
    int which = rem & 1, l = rem >> 1;
    int row = lane & 31;
    int pci = (j & 3) + ((j & 4) << 1) + ((lane >> 5) << 2);   // perm[s]
    float v = 0.f;
    if (which == 0) {
      if (row < 16)       v = rw[(l * 16 + row) * 16 + pci];
      else if (row == 16) v = mixw[l * 16 + pci];              // skip row
    } else {
      if (row < 16) v = (row == pci) ? 1.f : 0.f;              // identity
    }
    RA[r] = f2bf(v);
  }
}

// ---------------- fully fused WaveNet, 32x32 MFMA bodies ---------------------
__global__ __launch_bounds__(1024, 4) void wn_fused(
    const float* __restrict__ x, const float* __restrict__ in_w,
    const float* __restrict__ in_b,
    const ushort* __restrict__ WA, const ushort* __restrict__ RA,
    const float* __restrict__ hid_b, const float* __restrict__ res_b,
    const float* __restrict__ mix_w, const float* __restrict__ mix_b,
    float* __restrict__ outp) {
  __shared__ ushort sbuf[2][NSLOT * 16];   // 2 x 69632 B, swizzled [t][16ch] bf16

  int tid = threadIdx.x;
  int b = blockIdx.x & 7, tile = blockIdx.x >> 3;   // XCD<->batch affinity
  int t0 = tile * TILE;
  char* lds = (char*)sbuf;

  // ---- stage: input 1x1 conv into buf0 over tau in [-1152, 1024) ----
  for (int r = tid; r < NSLOT; r += 1024) {
    int t = t0 + r - BASEI;
    uint pk[8];
    if (t >= 0) {
      float xv = x[b * TT + t];
#pragma unroll
      for (int c = 0; c < 8; ++c) {
        float lo = fmaf(in_w[2 * c], xv, in_b[2 * c]);
        float hi = fmaf(in_w[2 * c + 1], xv, in_b[2 * c + 1]);
        pk[c] = cvtpk(lo, hi);
      }
    } else {
#pragma unroll
      for (int c = 0; c < 8; ++c) pk[c] = 0u;     // causal zero pad
    }
    // channel-permuted word order
    *(u32x4*)(lds + swz(r, 0))  = (u32x4){pk[0], pk[1], pk[4], pk[5]};
    *(u32x4*)(lds + swz(r, 16)) = (u32x4){pk[2], pk[3], pk[6], pk[7]};
  }
  __syncthreads();

  int lane = tid & 63, w = tid >> 6;
  int col32 = lane & 31, hi = lane >> 5;
  int oG  = hi << 4;          // B-frag load AND res-write byte offset (folded)
  int X = w * 32 + col32;     // this lane's output t (chunk A); B = X+512
  float skipA = 0.f, skipB = 0.f;
  int cur = 0;

  for (int i = 0; i < LL; ++i) {
    int D = 1 << (i & 7);
    int ost = (i < 7) ? -1024 : ((i < 15) ? -512 : 0);   // 512-rounded spans
    bool last = (i == LL - 1);

    const s16x8* wa = (const s16x8*)(WA + (size_t)i * 1536);
    s16x8 wa0 = wa[lane];            // tap k=0 (prescaled)
    s16x8 wa1 = wa[64 + lane];       // tap k=1
    s16x8 wa2 = wa[128 + lane];      // tap k=2
    const s16x8* rp = (const s16x8*)(RA + (size_t)i * 1024);
    s16x8 ra1 = rp[lane];            // res weights + mix row 16
    s16x8 ra2 = rp[64 + lane];       // identity (residual add)

    // bias fragments, prescaled to exp2 domain
    f32x4 hb0 = *(const f32x4*)(hid_b + i * 32 + 4 * hi);
    f32x4 hb1 = *(const f32x4*)(hid_b + i * 32 + 8 + 4 * hi);
    f32x4 hb2 = *(const f32x4*)(hid_b + i * 32 + 16 + 4 * hi);
    f32x4 hb3 = *(const f32x4*)(hid_b + i * 32 + 24 + 4 * hi);
    f32x16 bini;
#pragma unroll
    for (int q = 0; q < 4; ++q) {
      bini[q] = hb0[q] * S_T; bini[4 + q] = hb1[q] * S_T;
      bini[8 + q] = hb2[q] * S_S; bini[12 + q] = hb3[q] * S_S;
    }
    f32x4 rb0 = *(const f32x4*)(res_b + i * 16 + 4 * hi);
    f32x4 rb1 = *(const f32x4*)(res_b + i * 16 + 8 + 4 * hi);
    f32x16 rini;
#pragma unroll
    for (int q = 0; q < 4; ++q) {
      rini[q] = rb0[q]; rini[4 + q] = rb1[q];
      rini[8 + q] = 0.f; rini[12 + q] = 0.f;
    }
    f32x4 mwA, mwB;
    if (last) {                       // only layer 15 needs the mix vector
      mwA = *(const f32x4*)(mix_w + i * 16 + 4 * hi);
      mwB = *(const f32x4*)(mix_w + i * 16 + 8 + 4 * hi);
    }

    int rb = cur * BUFB;
    int wdelta = cur ? -BUFB : BUFB;
    int u0 = ost + X + BASEI;
    // oG folded into bases (bit-4 XOR commutes with all later adds)
    int A2 = (rb + swzb(u0)) ^ oG;
    int A1 = (rb + swzb(u0 - D)) ^ oG;
    int A0 = (rb + swzb(u0 - 2 * D)) ^ oG;
    int AW = A2 + wdelta;
    int tb0 = t0 + ost + X;

    // NB bodies: NB-2 halo, then output A, output B. Depth-1 tap pipeline.
    auto run = [&](auto nbc) {
      constexpr int NB = decltype(nbc)::value;
      s16x8 c0 = *(const s16x8*)(lds + A0);
      s16x8 c1 = *(const s16x8*)(lds + A1);
      s16x8 c2 = *(const s16x8*)(lds + A2);
#pragma unroll
      for (int bb = 0; bb < NB; ++bb) {
        const int mode = (bb < NB - 2) ? 0 : ((bb == NB - 2) ? 1 : 2);
        s16x8 n0, n1, n2;
        if (bb + 1 < NB) {        // prefetch next body's taps
          n0 = *(const s16x8*)(lds + A0 + (bb + 1) * 16384);
          n1 = *(const s16x8*)(lds + A1 + (bb + 1) * 16384);
          n2 = *(const s16x8*)(lds + A2 + (bb + 1) * 16384);
        }

        f32x16 acc = mfma32(wa0, c0, bini);
        acc = mfma32(wa1, c1, acc);
        acc = mfma32(wa2, c2, acc);

        // gated = (E-1)/((E+1)(F+1)); packed-f32 arithmetic, exp2 domain
        f32p2 G[4];
#pragma unroll
        for (int p = 0; p < 4; ++p) {
          f32p2 E = {fexp2(acc[2 * p]), fexp2(acc[2 * p + 1])};
          f32p2 F = {fexp2(acc[2 * p + 8]), fexp2(acc[2 * p + 9])};
          f32p2 num = E - 1.f;
          f32p2 den = (E + 1.f) * (F + 1.f);
          f32p2 R = {__builtin_amdgcn_rcpf(den.x), __builtin_amdgcn_rcpf(den.y)};
          G[p] = num * R;
        }

        if (!last) {
          uint O0 = cvtpk(G[0].x, G[0].y);
          uint O1 = cvtpk(G[1].x, G[1].y);
          uint O2 = cvtpk(G[2].x, G[2].y);
          uint O3 = cvtpk(G[3].x, G[3].y);
          u32x4 gw = {O0, O1, O2, O3};
          s16x8 gb = __builtin_bit_cast(s16x8, gw);

          f32x16 accr = mfma32(ra1, gb, rini);   // R@gates + res_b; row16=mix
          accr = mfma32(ra2, c2, accr);          // + identity @ center taps

          if (mode == 1) skipA += accr[8];       // row16 (hi=1 adds 0)
          else if (mode == 2) skipB += accr[8];

          uint o0 = cvtpk(accr[0], accr[1]);
          uint o1 = cvtpk(accr[2], accr[3]);
          uint o2 = cvtpk(accr[4], accr[5]);
          uint o3 = cvtpk(accr[6], accr[7]);
          if (mode == 0 && (tb0 + 512 * bb) < 0) { o0 = o1 = o2 = o3 = 0u; }
          *(u32x4*)(lds + AW + bb * 16384) = (u32x4){o0, o1, o2, o3};
        } else {
          float s = G[0].x * mwA[0];
          s = fmaf(G[0].y, mwA[1], s);
          s = fmaf(G[1].x, mwA[2], s);
          s = fmaf(G[1].y, mwA[3], s);
          s = fmaf(G[2].x, mwB[0], s);
          s = fmaf(G[2].y, mwB[1], s);
          s = fmaf(G[3].x, mwB[2], s);
          s = fmaf(G[3].y, mwB[3], s);
          if (mode == 1) skipA += s; else skipB += s;
        }

        c0 = n0; c1 = n1; c2 = n2;   // renamed away by full unroll
      }
    };

    if (i < 7)       run(IC<4>{});
    else if (i < 15) run(IC<3>{});
    else             run(IC<2>{});

    __syncthreads();
    cur ^= 1;
  }

  // epilogue: sum hi halves, write output directly
  float totA = skipA + __shfl_xor(skipA, 32);
  float totB = skipB + __shfl_xor(skipB, 32);
  if (hi == 0) {
    float mb = mix_b[0];
    int base = b * TT + t0 + X;
    outp[base] = totA + mb;
    outp[base + 512] = totB + mb;
  }
}

extern "C" void kernel_launch(void* const* d_in, const int* in_sizes, int n_in,
                              void* d_out, int out_size, void* d_ws, size_t ws_size,
                              hipStream_t stream) {
  const float* x     = (const float*)d_in[0];
  const float* in_w  = (const float*)d_in[1];
  const float* in_b  = (const float*)d_in[2];
  const float* hid_w = (const float*)d_in[3];
  const float* hid_b = (const float*)d_in[4];
  const float* res_w = (const float*)d_in[5];
  const float* res_b = (const float*)d_in[6];
  const float* mix_w = (const float*)d_in[7];
  const float* mix_b = (const float*)d_in[8];
  float* outp = (float*)d_out;

  ushort* WA = (ushort*)d_ws;          // 24576 ushorts
  ushort* RA = WA + 24576;             // 16384 ushorts

  wn_prep<<<160, 256, 0, stream>>>(hid_w, res_w, mix_w, WA, RA);
  wn_fused<<<BB * (TT / TILE), 1024, 0, stream>>>(
      x, in_w, in_b, WA, RA, hid_b, res_b, mix_w, mix_b, outp);
}